// Round 2
// baseline (225.063 us; speedup 1.0000x reference)
//
#include <hip/hip_runtime.h>
#include <hip/hip_bf16.h>

#define B_TOT 8192
#define FT    256
#define NREL  4
#define DEG   16

typedef __attribute__((ext_vector_type(8))) short bf16x8;
typedef __attribute__((ext_vector_type(4))) float f32x4;

static __device__ __forceinline__ unsigned short f2bf(float x) {
    union { float f; unsigned int u; } c; c.f = x;
    unsigned int u = c.u;
    u += 0x7fffu + ((u >> 16) & 1u);   // round-to-nearest-even
    return (unsigned short)(u >> 16);
}

// ---------- kernel 0: W [4][f][o] fp32 -> Wt [4][o][f] bf16 ----------
__global__ __launch_bounds__(256) void wtrans_k(const float* __restrict__ W,
                                                unsigned short* __restrict__ Wt) {
    int ro = blockIdx.x;            // r*256 + o
    int f  = threadIdx.x;
    int r  = ro >> 8, o = ro & 255;
    float w = W[((size_t)(r * FT + f)) * 256 + o];
    Wt[(size_t)ro * FT + f] = f2bf(w);
}

// ---------- kernel 1: gather + mean -> v [4][8192][256] bf16 ----------
__global__ __launch_bounds__(256) void gather_mean_k(const float* __restrict__ feat,
                                                     const int* __restrict__ nidx,
                                                     unsigned short* __restrict__ v) {
    int wave = threadIdx.x >> 6;
    int lane = threadIdx.x & 63;
    int task = blockIdx.x * 4 + wave;      // 0..32767
    int b = task >> 2, r = task & 3;
    const int* idx = nidx + ((size_t)b * NREL + r) * DEG;  // 64B aligned
    int4 i0 = *(const int4*)(idx);
    int4 i1 = *(const int4*)(idx + 4);
    int4 i2 = *(const int4*)(idx + 8);
    int4 i3 = *(const int4*)(idx + 12);
    float4 s = make_float4(0.f, 0.f, 0.f, 0.f);
#define ACC(nn) { const float4 x = ((const float4*)(feat + (size_t)(nn) * FT))[lane]; \
                  s.x += x.x; s.y += x.y; s.z += x.z; s.w += x.w; }
    ACC(i0.x) ACC(i0.y) ACC(i0.z) ACC(i0.w)
    ACC(i1.x) ACC(i1.y) ACC(i1.z) ACC(i1.w)
    ACC(i2.x) ACC(i2.y) ACC(i2.z) ACC(i2.w)
    ACC(i3.x) ACC(i3.y) ACC(i3.z) ACC(i3.w)
#undef ACC
    const float inv = 1.0f / 16.0f;
    ushort4 o;
    o.x = f2bf(s.x * inv); o.y = f2bf(s.y * inv);
    o.z = f2bf(s.z * inv); o.w = f2bf(s.w * inv);
    *(ushort4*)(v + ((size_t)r * B_TOT + b) * FT + 4 * lane) = o;
}

// ---------- kernel 2: per-relation GEMM + bias + PReLU + mean ----------
// v  : [4][8192][256] bf16 (A, row-major K-contig)
// Wt : [4][256][256]  bf16 (B^T: [o][f], so B loads like A from [n][k])
__global__ __launch_bounds__(256) void gemm_k(const unsigned short* __restrict__ v,
                                              const unsigned short* __restrict__ Wt,
                                              const float* __restrict__ bias,
                                              const float* __restrict__ prelu,
                                              float* __restrict__ out) {
    __shared__ unsigned short As[64][264];  // +8 pad: 2-way bank alias only (free)
    __shared__ unsigned short Bs[64][264];
    int tid  = threadIdx.x;
    int lane = tid & 63, w = tid >> 6;
    int wm = w >> 1, wn = w & 1;            // 2x2 wave grid, 32x32 each
    int mrow = lane & 15, quad = lane >> 4;
    int m0 = blockIdx.x * 64, n0 = blockIdx.y * 64;
    float pa = prelu[0];

    f32x4 accO[2][2] = {};
    int ocol0 = n0 + wn * 32 + mrow;

    for (int r = 0; r < NREL; ++r) {
        const unsigned short* Ag = v  + ((size_t)r * B_TOT + m0) * FT;
        const unsigned short* Bg = Wt + ((size_t)r * 256  + n0) * FT;
#pragma unroll
        for (int i = 0; i < 8; ++i) {       // 2048 8-elem units; 32 units per 256-wide row
            int u = tid + i * 256;
            int row = u >> 5, c8 = (u & 31) * 8;
            *(int4*)(&As[row][c8]) = *(const int4*)(Ag + row * FT + c8);
            *(int4*)(&Bs[row][c8]) = *(const int4*)(Bg + row * FT + c8);
        }
        __syncthreads();

        f32x4 acc[2][2] = {};
#pragma unroll
        for (int kk = 0; kk < 8; ++kk) {
            int k0 = kk * 32 + quad * 8;
            bf16x8 a0 = *(const bf16x8*)&As[wm * 32 + mrow][k0];
            bf16x8 a1 = *(const bf16x8*)&As[wm * 32 + 16 + mrow][k0];
            bf16x8 b0 = *(const bf16x8*)&Bs[wn * 32 + mrow][k0];
            bf16x8 b1 = *(const bf16x8*)&Bs[wn * 32 + 16 + mrow][k0];
            acc[0][0] = __builtin_amdgcn_mfma_f32_16x16x32_bf16(a0, b0, acc[0][0], 0, 0, 0);
            acc[1][0] = __builtin_amdgcn_mfma_f32_16x16x32_bf16(a1, b0, acc[1][0], 0, 0, 0);
            acc[0][1] = __builtin_amdgcn_mfma_f32_16x16x32_bf16(a0, b1, acc[0][1], 0, 0, 0);
            acc[1][1] = __builtin_amdgcn_mfma_f32_16x16x32_bf16(a1, b1, acc[1][1], 0, 0, 0);
        }
        __syncthreads();   // before next relation overwrites LDS

        float b0v = bias[r * 256 + ocol0];
        float b1v = bias[r * 256 + ocol0 + 16];
#pragma unroll
        for (int mt = 0; mt < 2; ++mt)
#pragma unroll
            for (int i = 0; i < 4; ++i) {
                float h0 = acc[mt][0][i] + b0v; h0 = (h0 >= 0.f) ? h0 : pa * h0;
                float h1 = acc[mt][1][i] + b1v; h1 = (h1 >= 0.f) ? h1 : pa * h1;
                accO[mt][0][i] += h0;
                accO[mt][1][i] += h1;
            }
    }

    // C/D layout: col = lane&15, row = quad*4 + i
#pragma unroll
    for (int mt = 0; mt < 2; ++mt)
#pragma unroll
        for (int i = 0; i < 4; ++i) {
            int row = m0 + wm * 32 + mt * 16 + quad * 4 + i;
            out[(size_t)row * 256 + ocol0]      = accO[mt][0][i] * 0.25f;
            out[(size_t)row * 256 + ocol0 + 16] = accO[mt][1][i] * 0.25f;
        }
}

extern "C" void kernel_launch(void* const* d_in, const int* in_sizes, int n_in,
                              void* d_out, int out_size, void* d_ws, size_t ws_size,
                              hipStream_t stream) {
    const float* feat  = (const float*)d_in[0];   // [100000,256] f32
    const int*   nidx  = (const int*)  d_in[1];   // [8192,4,16] i32
    const float* W     = (const float*)d_in[2];   // [4,256,256] f32
    const float* bias  = (const float*)d_in[3];   // [4,256] f32
    const float* prelu = (const float*)d_in[4];   // [1] f32
    // d_in[5] node_list, d_in[6] k: unused by reference
    float* out = (float*)d_out;                   // [8192,256] f32

    unsigned short* v  = (unsigned short*)d_ws;                 // 16 MB
    unsigned short* Wt = v + (size_t)NREL * B_TOT * FT;         // 512 KB

    wtrans_k<<<NREL * 256, 256, 0, stream>>>(W, Wt);
    gather_mean_k<<<B_TOT, 256, 0, stream>>>(feat, nidx, v);
    gemm_k<<<dim3(B_TOT / 64, 256 / 64), 256, 0, stream>>>(v, Wt, bias, prelu, out);
}

// Round 3
// 213.342 us; speedup vs baseline: 1.0549x; 1.0549x over previous
//
#include <hip/hip_runtime.h>
#include <hip/hip_bf16.h>

#define B_TOT 8192
#define FT    256
#define NREL  4
#define DEG   16

typedef __attribute__((ext_vector_type(8))) short bf16x8;
typedef __attribute__((ext_vector_type(4))) float f32x4;

static __device__ __forceinline__ unsigned short f2bf(float x) {
    union { float f; unsigned int u; } c; c.f = x;
    unsigned int u = c.u;
    u += 0x7fffu + ((u >> 16) & 1u);   // round-to-nearest-even
    return (unsigned short)(u >> 16);
}
static __device__ __forceinline__ float bf2f(unsigned short h) {
    union { unsigned int u; float f; } c; c.u = ((unsigned int)h) << 16;
    return c.f;
}

// ---------- kernel A: features f32 -> bf16 table (streaming) ----------
__global__ __launch_bounds__(256) void cvt_feat_k(const float* __restrict__ f,
                                                  unsigned short* __restrict__ fb,
                                                  int n4) {
    int i = blockIdx.x * 256 + threadIdx.x;
    if (i < n4) {
        float4 x = ((const float4*)f)[i];
        ushort4 o;
        o.x = f2bf(x.x); o.y = f2bf(x.y); o.z = f2bf(x.z); o.w = f2bf(x.w);
        ((ushort4*)fb)[i] = o;
    }
}

// ---------- kernel 0: W [4][f][o] fp32 -> Wt [4][o][f] bf16 (LDS transpose) ----------
__global__ __launch_bounds__(256) void wtrans_k(const float* __restrict__ W,
                                                unsigned short* __restrict__ Wt) {
    __shared__ float t[64][65];   // +1 pad
    int r = blockIdx.z, ft = blockIdx.y, ot = blockIdx.x;
    int c = threadIdx.x & 63, rw = threadIdx.x >> 6;
    const float* src = W + ((size_t)r * 256 + ft * 64) * 256 + ot * 64;
#pragma unroll
    for (int i = 0; i < 16; ++i) {
        int row = i * 4 + rw;
        t[row][c] = src[(size_t)row * 256 + c];     // coalesced over c
    }
    __syncthreads();
    unsigned short* dst = Wt + ((size_t)r * 256 + ot * 64) * 256 + ft * 64;
#pragma unroll
    for (int i = 0; i < 16; ++i) {
        int row = i * 4 + rw;
        dst[(size_t)row * 256 + c] = f2bf(t[c][row]); // coalesced over c; LDS col read (stride 65: free)
    }
}

// ---------- kernel 1a: gather + mean from bf16 table -> v [4][8192][256] bf16 ----------
__global__ __launch_bounds__(256) void gather_mean_bf16_k(const unsigned short* __restrict__ fb,
                                                          const int* __restrict__ nidx,
                                                          unsigned short* __restrict__ v) {
    int wave = threadIdx.x >> 6;
    int lane = threadIdx.x & 63;
    int task = blockIdx.x * 4 + wave;      // 0..32767
    int b = task >> 2, r = task & 3;
    const int* idx = nidx + ((size_t)b * NREL + r) * DEG;
    int4 i0 = *(const int4*)(idx);
    int4 i1 = *(const int4*)(idx + 4);
    int4 i2 = *(const int4*)(idx + 8);
    int4 i3 = *(const int4*)(idx + 12);
    float s0 = 0.f, s1 = 0.f, s2 = 0.f, s3 = 0.f;
#define ACC(nn) { const ushort4 x = ((const ushort4*)(fb + (size_t)(nn) * FT))[lane]; \
                  s0 += bf2f(x.x); s1 += bf2f(x.y); s2 += bf2f(x.z); s3 += bf2f(x.w); }
    ACC(i0.x) ACC(i0.y) ACC(i0.z) ACC(i0.w)
    ACC(i1.x) ACC(i1.y) ACC(i1.z) ACC(i1.w)
    ACC(i2.x) ACC(i2.y) ACC(i2.z) ACC(i2.w)
    ACC(i3.x) ACC(i3.y) ACC(i3.z) ACC(i3.w)
#undef ACC
    const float inv = 1.0f / 16.0f;
    ushort4 o;
    o.x = f2bf(s0 * inv); o.y = f2bf(s1 * inv);
    o.z = f2bf(s2 * inv); o.w = f2bf(s3 * inv);
    *(ushort4*)(v + ((size_t)r * B_TOT + b) * FT + 4 * lane) = o;
}

// ---------- kernel 1b: fp32-table fallback (if ws too small for bf16 table) ----------
__global__ __launch_bounds__(256) void gather_mean_k(const float* __restrict__ feat,
                                                     const int* __restrict__ nidx,
                                                     unsigned short* __restrict__ v) {
    int wave = threadIdx.x >> 6;
    int lane = threadIdx.x & 63;
    int task = blockIdx.x * 4 + wave;
    int b = task >> 2, r = task & 3;
    const int* idx = nidx + ((size_t)b * NREL + r) * DEG;
    int4 i0 = *(const int4*)(idx);
    int4 i1 = *(const int4*)(idx + 4);
    int4 i2 = *(const int4*)(idx + 8);
    int4 i3 = *(const int4*)(idx + 12);
    float4 s = make_float4(0.f, 0.f, 0.f, 0.f);
#define ACC(nn) { const float4 x = ((const float4*)(feat + (size_t)(nn) * FT))[lane]; \
                  s.x += x.x; s.y += x.y; s.z += x.z; s.w += x.w; }
    ACC(i0.x) ACC(i0.y) ACC(i0.z) ACC(i0.w)
    ACC(i1.x) ACC(i1.y) ACC(i1.z) ACC(i1.w)
    ACC(i2.x) ACC(i2.y) ACC(i2.z) ACC(i2.w)
    ACC(i3.x) ACC(i3.y) ACC(i3.z) ACC(i3.w)
#undef ACC
    const float inv = 1.0f / 16.0f;
    ushort4 o;
    o.x = f2bf(s.x * inv); o.y = f2bf(s.y * inv);
    o.z = f2bf(s.z * inv); o.w = f2bf(s.w * inv);
    *(ushort4*)(v + ((size_t)r * B_TOT + b) * FT + 4 * lane) = o;
}

// ---------- kernel 2: per-relation GEMM + bias + PReLU + mean ----------
__global__ __launch_bounds__(256) void gemm_k(const unsigned short* __restrict__ v,
                                              const unsigned short* __restrict__ Wt,
                                              const float* __restrict__ bias,
                                              const float* __restrict__ prelu,
                                              float* __restrict__ out) {
    __shared__ unsigned short As[64][264];  // +8 pad: 2-way bank alias only (free)
    __shared__ unsigned short Bs[64][264];
    int tid  = threadIdx.x;
    int lane = tid & 63, w = tid >> 6;
    int wm = w >> 1, wn = w & 1;            // 2x2 wave grid, 32x32 each
    int mrow = lane & 15, quad = lane >> 4;
    int m0 = blockIdx.x * 64, n0 = blockIdx.y * 64;
    float pa = prelu[0];

    f32x4 accO[2][2] = {};
    int ocol0 = n0 + wn * 32 + mrow;

    for (int r = 0; r < NREL; ++r) {
        const unsigned short* Ag = v  + ((size_t)r * B_TOT + m0) * FT;
        const unsigned short* Bg = Wt + ((size_t)r * 256  + n0) * FT;
#pragma unroll
        for (int i = 0; i < 8; ++i) {       // 2048 8-elem units; 32 per 256-wide row
            int u = tid + i * 256;
            int row = u >> 5, c8 = (u & 31) * 8;
            *(int4*)(&As[row][c8]) = *(const int4*)(Ag + row * FT + c8);
            *(int4*)(&Bs[row][c8]) = *(const int4*)(Bg + row * FT + c8);
        }
        __syncthreads();

        f32x4 acc[2][2] = {};
#pragma unroll
        for (int kk = 0; kk < 8; ++kk) {
            int k0 = kk * 32 + quad * 8;
            bf16x8 a0 = *(const bf16x8*)&As[wm * 32 + mrow][k0];
            bf16x8 a1 = *(const bf16x8*)&As[wm * 32 + 16 + mrow][k0];
            bf16x8 b0 = *(const bf16x8*)&Bs[wn * 32 + mrow][k0];
            bf16x8 b1 = *(const bf16x8*)&Bs[wn * 32 + 16 + mrow][k0];
            acc[0][0] = __builtin_amdgcn_mfma_f32_16x16x32_bf16(a0, b0, acc[0][0], 0, 0, 0);
            acc[1][0] = __builtin_amdgcn_mfma_f32_16x16x32_bf16(a1, b0, acc[1][0], 0, 0, 0);
            acc[0][1] = __builtin_amdgcn_mfma_f32_16x16x32_bf16(a0, b1, acc[0][1], 0, 0, 0);
            acc[1][1] = __builtin_amdgcn_mfma_f32_16x16x32_bf16(a1, b1, acc[1][1], 0, 0, 0);
        }
        __syncthreads();

        float b0v = bias[r * 256 + ocol0];
        float b1v = bias[r * 256 + ocol0 + 16];
#pragma unroll
        for (int mt = 0; mt < 2; ++mt)
#pragma unroll
            for (int i = 0; i < 4; ++i) {
                float h0 = acc[mt][0][i] + b0v; h0 = (h0 >= 0.f) ? h0 : pa * h0;
                float h1 = acc[mt][1][i] + b1v; h1 = (h1 >= 0.f) ? h1 : pa * h1;
                accO[mt][0][i] += h0;
                accO[mt][1][i] += h1;
            }
    }

    // C/D layout: col = lane&15, row = quad*4 + i
#pragma unroll
    for (int mt = 0; mt < 2; ++mt)
#pragma unroll
        for (int i = 0; i < 4; ++i) {
            int row = m0 + wm * 32 + mt * 16 + quad * 4 + i;
            out[(size_t)row * 256 + ocol0]      = accO[mt][0][i] * 0.25f;
            out[(size_t)row * 256 + ocol0 + 16] = accO[mt][1][i] * 0.25f;
        }
}

extern "C" void kernel_launch(void* const* d_in, const int* in_sizes, int n_in,
                              void* d_out, int out_size, void* d_ws, size_t ws_size,
                              hipStream_t stream) {
    const float* feat  = (const float*)d_in[0];   // [100000,256] f32
    const int*   nidx  = (const int*)  d_in[1];   // [8192,4,16] i32
    const float* W     = (const float*)d_in[2];   // [4,256,256] f32
    const float* bias  = (const float*)d_in[3];   // [4,256] f32
    const float* prelu = (const float*)d_in[4];   // [1] f32
    float* out = (float*)d_out;                   // [8192,256] f32

    const size_t feat_elems = (size_t)in_sizes[0];          // 25,600,000
    const size_t fb_bytes = feat_elems * 2;                 // 51.2 MB
    const size_t v_bytes  = (size_t)NREL * B_TOT * FT * 2;  // 16.78 MB
    const size_t wt_bytes = (size_t)NREL * 256 * FT * 2;    // 0.5 MB

    if (ws_size >= fb_bytes + v_bytes + wt_bytes) {
        unsigned short* fb = (unsigned short*)d_ws;
        unsigned short* v  = fb + feat_elems;
        unsigned short* Wt = v + (size_t)NREL * B_TOT * FT;
        int n4 = (int)(feat_elems / 4);
        cvt_feat_k<<<(n4 + 255) / 256, 256, 0, stream>>>(feat, fb, n4);
        wtrans_k<<<dim3(4, 4, 4), 256, 0, stream>>>(W, Wt);
        gather_mean_bf16_k<<<B_TOT, 256, 0, stream>>>(fb, nidx, v);
        gemm_k<<<dim3(B_TOT / 64, 256 / 64), 256, 0, stream>>>(v, Wt, bias, prelu, out);
    } else {
        unsigned short* v  = (unsigned short*)d_ws;
        unsigned short* Wt = v + (size_t)NREL * B_TOT * FT;
        wtrans_k<<<dim3(4, 4, 4), 256, 0, stream>>>(W, Wt);
        gather_mean_k<<<B_TOT, 256, 0, stream>>>(feat, nidx, v);
        gemm_k<<<dim3(B_TOT / 64, 256 / 64), 256, 0, stream>>>(v, Wt, bias, prelu, out);
    }
}